// Round 1
// baseline (5383.670 us; speedup 1.0000x reference)
//
#include <hip/hip_runtime.h>

#define THREADS 256
#define ROWS 16
#define DD 512
#define HIDN 512
#define TT 16
#define OUTN 7

// One block owns ROWS batch rows for the entire T-loop.
// Membrane state in registers; spikes as 512-bit ballot masks in LDS;
// dense part = xt @ [W_gc | W_d1_top] register-blocked fp32 GEMM;
// recurrent matmuls are spike-driven (sparse) weight-row accumulation.
__global__ __launch_bounds__(THREADS, 2)
void snn_fused_kernel(const float* __restrict__ x,
                      const float* __restrict__ Wgc, const float* __restrict__ bgc,
                      const float* __restrict__ Wpc, const float* __restrict__ bpc,
                      const float* __restrict__ Wd1, const float* __restrict__ bd1p,
                      const float* __restrict__ Wd2, const float* __restrict__ bd2,
                      float* __restrict__ out, int B)
{
    __shared__ float xs[ROWS * DD];                 // 32 KB x-tile
    __shared__ unsigned long long bits1[ROWS][8];   // gc spikes
    __shared__ unsigned long long bits2[ROWS][8];   // pc spikes
    __shared__ unsigned long long bits3[ROWS][8];   // s3 spikes

    const int tid  = threadIdx.x;
    const int lane = tid & 63;
    const int wave = tid >> 6;
    const size_t row0 = (size_t)blockIdx.x * ROWS;

    // persistent membrane state: features (tid, tid+256) x ROWS rows
    float m1a[ROWS], m1b[ROWS], m2a[ROWS], m2b[ROWS], m3a[ROWS], m3b[ROWS];
#pragma unroll
    for (int r = 0; r < ROWS; ++r) {
        m1a[r] = 0.f; m1b[r] = 0.f; m2a[r] = 0.f;
        m2b[r] = 0.f; m3a[r] = 0.f; m3b[r] = 0.f;
    }

    const float bg0 = bgc[tid],  bg1 = bgc[tid + 256];
    const float bp0 = bpc[tid],  bp1 = bpc[tid + 256];
    const float bd0 = bd1p[tid], bd1 = bd1p[tid + 256];

    float out_acc = 0.f;
    const int orow = tid / OUTN;
    const int ocol = tid - orow * OUTN;
    const bool owrite = (tid < ROWS * OUTN);

    for (int t = 0; t < TT; ++t) {
        __syncthreads();  // protect xs/bits reuse from previous iteration
        {
            const float4* src = reinterpret_cast<const float4*>(x + ((size_t)t * B + row0) * DD);
            float4* dst = reinterpret_cast<float4*>(xs);
#pragma unroll
            for (int u = 0; u < 8; ++u) dst[u * THREADS + tid] = src[u * THREADS + tid];
        }
        __syncthreads();

        // ---- dense GEMM: acc[r][c], c: 0,1 -> gc_in(tid,tid+256); 2,3 -> d1x(tid,tid+256)
        float a0[ROWS], a1[ROWS], a2[ROWS], a3[ROWS];
#pragma unroll
        for (int r = 0; r < ROWS; ++r) { a0[r] = 0.f; a1[r] = 0.f; a2[r] = 0.f; a3[r] = 0.f; }

        float w0[4], w1[4], w2[4], w3[4];
#pragma unroll
        for (int u = 0; u < 4; ++u) {
            const float* g = Wgc + (size_t)u * HIDN + tid;
            const float* d = Wd1 + (size_t)u * HIDN + tid;
            w0[u] = g[0]; w1[u] = g[256]; w2[u] = d[0]; w3[u] = d[256];
        }
#pragma unroll 1
        for (int kk = 0; kk < DD; kk += 4) {
            // prefetch next k-slice of weights while doing FMAs on current
            float n0[4], n1[4], n2[4], n3[4];
            const int kn = (kk + 4 < DD) ? (kk + 4) : 0;
#pragma unroll
            for (int u = 0; u < 4; ++u) {
                const float* g = Wgc + (size_t)(kn + u) * HIDN + tid;
                const float* d = Wd1 + (size_t)(kn + u) * HIDN + tid;
                n0[u] = g[0]; n1[u] = g[256]; n2[u] = d[0]; n3[u] = d[256];
            }
#pragma unroll
            for (int r = 0; r < ROWS; ++r) {
                const float4 xv = *reinterpret_cast<const float4*>(&xs[r * DD + kk]);
                a0[r] = fmaf(xv.x, w0[0], a0[r]);
                a0[r] = fmaf(xv.y, w0[1], a0[r]);
                a0[r] = fmaf(xv.z, w0[2], a0[r]);
                a0[r] = fmaf(xv.w, w0[3], a0[r]);
                a1[r] = fmaf(xv.x, w1[0], a1[r]);
                a1[r] = fmaf(xv.y, w1[1], a1[r]);
                a1[r] = fmaf(xv.z, w1[2], a1[r]);
                a1[r] = fmaf(xv.w, w1[3], a1[r]);
                a2[r] = fmaf(xv.x, w2[0], a2[r]);
                a2[r] = fmaf(xv.y, w2[1], a2[r]);
                a2[r] = fmaf(xv.z, w2[2], a2[r]);
                a2[r] = fmaf(xv.w, w2[3], a2[r]);
                a3[r] = fmaf(xv.x, w3[0], a3[r]);
                a3[r] = fmaf(xv.y, w3[1], a3[r]);
                a3[r] = fmaf(xv.z, w3[2], a3[r]);
                a3[r] = fmaf(xv.w, w3[3], a3[r]);
            }
#pragma unroll
            for (int u = 0; u < 4; ++u) { w0[u] = n0[u]; w1[u] = n1[u]; w2[u] = n2[u]; w3[u] = n3[u]; }
        }

        // ---- LIF layer 1 (gc): spikes -> bits1 via ballot
#pragma unroll
        for (int r = 0; r < ROWS; ++r) {
            const float i0 = a0[r] + bg0;
            const float v0 = m1a[r] + (i0 - m1a[r]) * 0.5f;
            const bool s0 = (v0 - 1.0f) > 0.0f;
            m1a[r] = s0 ? 0.0f : v0;
            const unsigned long long k0 = __ballot(s0);
            const float i1 = a1[r] + bg1;
            const float v1 = m1b[r] + (i1 - m1b[r]) * 0.5f;
            const bool s1 = (v1 - 1.0f) > 0.0f;
            m1b[r] = s1 ? 0.0f : v1;
            const unsigned long long k1 = __ballot(s1);
            if (lane == 0) { bits1[r][wave] = k0; bits1[r][4 + wave] = k1; }
        }
        __syncthreads();

        // ---- layer 2 (pc): pc_in = sum of W_pc rows over gc spikes + b_pc
#pragma unroll 1
        for (int r = 0; r < ROWS; ++r) {
            float p0 = bp0, p1 = bp1;
#pragma unroll 1
            for (int w = 0; w < 8; ++w) {
                unsigned long long m = bits1[r][w];
                while (m) {
                    const int b = __builtin_ctzll(m);
                    m &= (m - 1);
                    const float* wp = Wpc + (size_t)((w << 6) + b) * HIDN + tid;
                    p0 += wp[0];
                    p1 += wp[256];
                }
            }
            const float v0 = m2a[r] + (p0 - m2a[r]) * 0.5f;
            const bool s0 = (v0 - 1.0f) > 0.0f;
            m2a[r] = s0 ? 0.0f : v0;
            const unsigned long long k0 = __ballot(s0);
            const float v1 = m2b[r] + (p1 - m2b[r]) * 0.5f;
            const bool s1 = (v1 - 1.0f) > 0.0f;
            m2b[r] = s1 ? 0.0f : v1;
            const unsigned long long k1 = __ballot(s1);
            if (lane == 0) { bits2[r][wave] = k0; bits2[r][4 + wave] = k1; }
        }
        __syncthreads();

        // ---- layer 3 (dcn hidden): d1_in = x-part (a2,a3) + b_d1 + W_d1_bot rows over pc spikes
#pragma unroll 1
        for (int r = 0; r < ROWS; ++r) {
            float p0 = a2[r] + bd0, p1 = a3[r] + bd1;
#pragma unroll 1
            for (int w = 0; w < 8; ++w) {
                unsigned long long m = bits2[r][w];
                while (m) {
                    const int b = __builtin_ctzll(m);
                    m &= (m - 1);
                    const float* wp = Wd1 + (size_t)(DD + (w << 6) + b) * HIDN + tid;
                    p0 += wp[0];
                    p1 += wp[256];
                }
            }
            const float v0 = m3a[r] + (p0 - m3a[r]) * 0.5f;
            const bool s0 = (v0 - 1.0f) > 0.0f;
            m3a[r] = s0 ? 0.0f : v0;
            const unsigned long long k0 = __ballot(s0);
            const float v1 = m3b[r] + (p1 - m3b[r]) * 0.5f;
            const bool s1 = (v1 - 1.0f) > 0.0f;
            m3b[r] = s1 ? 0.0f : v1;
            const unsigned long long k1 = __ballot(s1);
            if (lane == 0) { bits3[r][wave] = k0; bits3[r][4 + wave] = k1; }
        }
        __syncthreads();

        // ---- output: out_acc += W_d2 rows over s3 spikes (threads 0..111 own (row,ocol))
        if (owrite) {
#pragma unroll 1
            for (int w = 0; w < 8; ++w) {
                unsigned long long m = bits3[orow][w];
                while (m) {
                    const int b = __builtin_ctzll(m);
                    m &= (m - 1);
                    out_acc += Wd2[(size_t)((w << 6) + b) * OUTN + ocol];
                }
            }
        }
    }

    if (owrite) {
        out[(row0 + orow) * OUTN + ocol] = out_acc * 0.0625f + bd2[ocol];
    }
}

extern "C" void kernel_launch(void* const* d_in, const int* in_sizes, int n_in,
                              void* d_out, int out_size, void* d_ws, size_t ws_size,
                              hipStream_t stream) {
    const float* x   = (const float*)d_in[0];
    const float* Wgc = (const float*)d_in[1];
    const float* bgc = (const float*)d_in[2];
    const float* Wpc = (const float*)d_in[3];
    const float* bpc = (const float*)d_in[4];
    const float* Wd1 = (const float*)d_in[5];
    const float* bd1 = (const float*)d_in[6];
    const float* Wd2 = (const float*)d_in[7];
    const float* bd2 = (const float*)d_in[8];
    const int B = in_sizes[0] / (TT * DD);

    dim3 grid(B / ROWS), block(THREADS);
    hipLaunchKernelGGL(snn_fused_kernel, grid, block, 0, stream,
                       x, Wgc, bgc, Wpc, bpc, Wd1, bd1, Wd2, bd2,
                       (float*)d_out, B);
}

// Round 2
// 4955.569 us; speedup vs baseline: 1.0864x; 1.0864x over previous
//
#include <hip/hip_runtime.h>

#define THREADS 256
#define ROWS 16
#define DD 512
#define HIDN 512
#define TT 16
#define OUTN 7

// async global->LDS, 16B per lane; LDS dest = wave-uniform base + lane*16
#define GLD_LDS(g, l) __builtin_amdgcn_global_load_lds(                     \
    (const __attribute__((address_space(1))) void*)(g),                     \
    (__attribute__((address_space(3))) void*)(l), 16, 0, 0)

// One block owns ROWS batch rows for the entire T-loop.
// Membrane state in registers (AGPR-parked); spikes as 512-bit ballot masks
// in LDS with a per-layer 16-bit row-summary so consumers skip empty rows;
// dense part = xt @ [W_gc | W_d1_top] ping-pong register-blocked fp32 GEMM;
// recurrent matmuls are spike-driven weight-row accumulation.
__global__ __launch_bounds__(THREADS, 2)
void snn_fused_kernel(const float* __restrict__ x,
                      const float* __restrict__ Wgc, const float* __restrict__ bgc,
                      const float* __restrict__ Wpc, const float* __restrict__ bpc,
                      const float* __restrict__ Wd1, const float* __restrict__ bd1p,
                      const float* __restrict__ Wd2, const float* __restrict__ bd2,
                      float* __restrict__ out, int B)
{
    __shared__ float xs[ROWS * DD];                 // 32 KB x-tile
    __shared__ unsigned long long bits1[ROWS][8];   // gc spikes
    __shared__ unsigned long long bits2[ROWS][8];   // pc spikes
    __shared__ unsigned long long bits3[ROWS][8];   // s3 spikes
    __shared__ unsigned int rowflag[3];             // per-layer "row has spikes" masks

    const int tid  = threadIdx.x;
    const int lane = tid & 63;
    const int wave = tid >> 6;
    const size_t row0 = (size_t)blockIdx.x * ROWS;

    float m1a[ROWS], m1b[ROWS], m2a[ROWS], m2b[ROWS], m3a[ROWS], m3b[ROWS];
#pragma unroll
    for (int r = 0; r < ROWS; ++r) {
        m1a[r] = 0.f; m1b[r] = 0.f; m2a[r] = 0.f;
        m2b[r] = 0.f; m3a[r] = 0.f; m3b[r] = 0.f;
    }

    const float bg0 = bgc[tid],  bg1 = bgc[tid + 256];
    const float bp0 = bpc[tid],  bp1 = bpc[tid + 256];
    const float bd0 = bd1p[tid], bd1 = bd1p[tid + 256];

    float out_acc = 0.f;
    const int orow = tid / OUTN;
    const int ocol = tid - orow * OUTN;
    const bool owrite = (tid < ROWS * OUTN);

    // ---- pre-loop: zero flags, async-stage xs for t=0
    if (tid < 3) rowflag[tid] = 0;
    {
        const float* src = x + row0 * DD;
#pragma unroll
        for (int u = 0; u < 8; ++u)
            GLD_LDS(src + ((u * THREADS + tid) << 2), xs + ((u * THREADS + wave * 64) << 2));
    }
    __syncthreads();

    for (int t = 0; t < TT; ++t) {
        // ================= dense GEMM over xs (ping-pong weight prefetch) ======
        // acc cols: a0/a1 -> gc_in(tid,tid+256); a2/a3 -> d1x(tid,tid+256)
        float a0[ROWS], a1[ROWS], a2[ROWS], a3[ROWS];
#pragma unroll
        for (int r = 0; r < ROWS; ++r) { a0[r] = 0.f; a1[r] = 0.f; a2[r] = 0.f; a3[r] = 0.f; }

        const float* gp = Wgc + tid;
        const float* dp = Wd1 + tid;

        float wA0[4], wA1[4], wA2[4], wA3[4];
        float wB0[4], wB1[4], wB2[4], wB3[4];
#pragma unroll
        for (int u = 0; u < 4; ++u) {
            const size_t o = (size_t)u * HIDN;
            wA0[u] = gp[o]; wA1[u] = gp[o + 256];
            wA2[u] = dp[o]; wA3[u] = dp[o + 256];
        }
#pragma unroll 1
        for (int kk = 0; kk < DD; kk += 8) {
#pragma unroll
            for (int u = 0; u < 4; ++u) {     // prefetch B-set at kk+4
                const size_t o = (size_t)(kk + 4 + u) * HIDN;
                wB0[u] = gp[o]; wB1[u] = gp[o + 256];
                wB2[u] = dp[o]; wB3[u] = dp[o + 256];
            }
#pragma unroll
            for (int r = 0; r < ROWS; ++r) {  // FMA with A-set at kk
                const float4 xv = *reinterpret_cast<const float4*>(&xs[r * DD + kk]);
                a0[r] = fmaf(xv.x, wA0[0], a0[r]); a0[r] = fmaf(xv.y, wA0[1], a0[r]);
                a0[r] = fmaf(xv.z, wA0[2], a0[r]); a0[r] = fmaf(xv.w, wA0[3], a0[r]);
                a1[r] = fmaf(xv.x, wA1[0], a1[r]); a1[r] = fmaf(xv.y, wA1[1], a1[r]);
                a1[r] = fmaf(xv.z, wA1[2], a1[r]); a1[r] = fmaf(xv.w, wA1[3], a1[r]);
                a2[r] = fmaf(xv.x, wA2[0], a2[r]); a2[r] = fmaf(xv.y, wA2[1], a2[r]);
                a2[r] = fmaf(xv.z, wA2[2], a2[r]); a2[r] = fmaf(xv.w, wA2[3], a2[r]);
                a3[r] = fmaf(xv.x, wA3[0], a3[r]); a3[r] = fmaf(xv.y, wA3[1], a3[r]);
                a3[r] = fmaf(xv.z, wA3[2], a3[r]); a3[r] = fmaf(xv.w, wA3[3], a3[r]);
            }
            const int k2 = (kk + 8) & (DD - 1);
#pragma unroll
            for (int u = 0; u < 4; ++u) {     // prefetch A-set at kk+8 (wraps at end)
                const size_t o = (size_t)(k2 + u) * HIDN;
                wA0[u] = gp[o]; wA1[u] = gp[o + 256];
                wA2[u] = dp[o]; wA3[u] = dp[o + 256];
            }
#pragma unroll
            for (int r = 0; r < ROWS; ++r) {  // FMA with B-set at kk+4
                const float4 xv = *reinterpret_cast<const float4*>(&xs[r * DD + kk + 4]);
                a0[r] = fmaf(xv.x, wB0[0], a0[r]); a0[r] = fmaf(xv.y, wB0[1], a0[r]);
                a0[r] = fmaf(xv.z, wB0[2], a0[r]); a0[r] = fmaf(xv.w, wB0[3], a0[r]);
                a1[r] = fmaf(xv.x, wB1[0], a1[r]); a1[r] = fmaf(xv.y, wB1[1], a1[r]);
                a1[r] = fmaf(xv.z, wB1[2], a1[r]); a1[r] = fmaf(xv.w, wB1[3], a1[r]);
                a2[r] = fmaf(xv.x, wB2[0], a2[r]); a2[r] = fmaf(xv.y, wB2[1], a2[r]);
                a2[r] = fmaf(xv.z, wB2[2], a2[r]); a2[r] = fmaf(xv.w, wB2[3], a2[r]);
                a3[r] = fmaf(xv.x, wB3[0], a3[r]); a3[r] = fmaf(xv.y, wB3[1], a3[r]);
                a3[r] = fmaf(xv.z, wB3[2], a3[r]); a3[r] = fmaf(xv.w, wB3[3], a3[r]);
            }
        }

        // ================= LIF layer 1 (gc) -> bits1 + rowflag[0] ==============
#pragma unroll
        for (int r = 0; r < ROWS; ++r) {
            const float v0 = m1a[r] + ((a0[r] + bg0) - m1a[r]) * 0.5f;
            const bool s0 = (v0 - 1.0f) > 0.0f;
            m1a[r] = s0 ? 0.0f : v0;
            const unsigned long long k0 = __ballot(s0);
            const float v1 = m1b[r] + ((a1[r] + bg1) - m1b[r]) * 0.5f;
            const bool s1 = (v1 - 1.0f) > 0.0f;
            m1b[r] = s1 ? 0.0f : v1;
            const unsigned long long k1 = __ballot(s1);
            if (lane == 0) {
                bits1[r][wave] = k0; bits1[r][4 + wave] = k1;
                if (k0 | k1) atomicOr(&rowflag[0], 1u << r);
            }
        }
        __syncthreads();                                   // barrier A

        // zero flag2 for this t (writer = layer3, after barrier B)
        if (tid == 0) rowflag[2] = 0;

        // async-stage next t's x-tile; drains at barrier B
        if (t + 1 < TT) {
            const float* src = x + (((size_t)(t + 1) * B) + row0) * DD;
#pragma unroll
            for (int u = 0; u < 8; ++u)
                GLD_LDS(src + ((u * THREADS + tid) << 2), xs + ((u * THREADS + wave * 64) << 2));
        }

        // ================= layer 2 (pc): sparse bits1 -> bits2 + rowflag[1] ====
        {
            const unsigned int rf = rowflag[0];
#pragma unroll 1
            for (int r = 0; r < ROWS; ++r) {
                float p0 = bp0, p1 = bp1;
                if (rf & (1u << r)) {
#pragma unroll 1
                    for (int w = 0; w < 8; ++w) {
                        unsigned long long m = bits1[r][w];
                        while (m) {
                            const int b = __builtin_ctzll(m); m &= (m - 1);
                            const float* wp = Wpc + (size_t)((w << 6) + b) * HIDN + tid;
                            p0 += wp[0]; p1 += wp[256];
                        }
                    }
                }
                const float v0 = m2a[r] + (p0 - m2a[r]) * 0.5f;
                const bool s0 = (v0 - 1.0f) > 0.0f;
                m2a[r] = s0 ? 0.0f : v0;
                const unsigned long long k0 = __ballot(s0);
                const float v1 = m2b[r] + (p1 - m2b[r]) * 0.5f;
                const bool s1 = (v1 - 1.0f) > 0.0f;
                m2b[r] = s1 ? 0.0f : v1;
                const unsigned long long k1 = __ballot(s1);
                if (lane == 0) {
                    bits2[r][wave] = k0; bits2[r][4 + wave] = k1;
                    if (k0 | k1) atomicOr(&rowflag[1], 1u << r);
                }
            }
        }
        __syncthreads();                                   // barrier B

        // zero flag0 for next t (writer = LIF1(t+1), after barrier C)
        if (tid == 0) rowflag[0] = 0;

        // ================= layer 3 (dcn): a2/a3 + sparse bits2 -> bits3 ========
        {
            const unsigned int rf = rowflag[1];
#pragma unroll 1
            for (int r = 0; r < ROWS; ++r) {
                float p0 = a2[r] + bd0, p1 = a3[r] + bd1;
                if (rf & (1u << r)) {
#pragma unroll 1
                    for (int w = 0; w < 8; ++w) {
                        unsigned long long m = bits2[r][w];
                        while (m) {
                            const int b = __builtin_ctzll(m); m &= (m - 1);
                            const float* wp = Wd1 + (size_t)(DD + (w << 6) + b) * HIDN + tid;
                            p0 += wp[0]; p1 += wp[256];
                        }
                    }
                }
                const float v0 = m3a[r] + (p0 - m3a[r]) * 0.5f;
                const bool s0 = (v0 - 1.0f) > 0.0f;
                m3a[r] = s0 ? 0.0f : v0;
                const unsigned long long k0 = __ballot(s0);
                const float v1 = m3b[r] + (p1 - m3b[r]) * 0.5f;
                const bool s1 = (v1 - 1.0f) > 0.0f;
                m3b[r] = s1 ? 0.0f : v1;
                const unsigned long long k1 = __ballot(s1);
                if (lane == 0) {
                    bits3[r][wave] = k0; bits3[r][4 + wave] = k1;
                    if (k0 | k1) atomicOr(&rowflag[2], 1u << r);
                }
            }
        }
        __syncthreads();                                   // barrier C

        // zero flag1 for next t (writer = layer2(t+1), after barrier A(t+1))
        if (tid == 0) rowflag[1] = 0;

        // ================= output accumulation over s3 spikes ==================
        {
            const unsigned int rf = rowflag[2];
            if (owrite && (rf & (1u << orow))) {
#pragma unroll 1
                for (int w = 0; w < 8; ++w) {
                    unsigned long long m = bits3[orow][w];
                    while (m) {
                        const int b = __builtin_ctzll(m); m &= (m - 1);
                        out_acc += Wd2[(size_t)((w << 6) + b) * OUTN + ocol];
                    }
                }
            }
        }
        // next-t xs already staged (drained at barrier B); barrier C protects
        // bits3/flags; loop-top GEMM reads xs which no one writes until A(t+1).
    }

    if (owrite) {
        out[(row0 + orow) * OUTN + ocol] = out_acc * 0.0625f + bd2[ocol];
    }
}

extern "C" void kernel_launch(void* const* d_in, const int* in_sizes, int n_in,
                              void* d_out, int out_size, void* d_ws, size_t ws_size,
                              hipStream_t stream) {
    const float* x   = (const float*)d_in[0];
    const float* Wgc = (const float*)d_in[1];
    const float* bgc = (const float*)d_in[2];
    const float* Wpc = (const float*)d_in[3];
    const float* bpc = (const float*)d_in[4];
    const float* Wd1 = (const float*)d_in[5];
    const float* bd1 = (const float*)d_in[6];
    const float* Wd2 = (const float*)d_in[7];
    const float* bd2 = (const float*)d_in[8];
    const int B = in_sizes[0] / (TT * DD);

    dim3 grid(B / ROWS), block(THREADS);
    hipLaunchKernelGGL(snn_fused_kernel, grid, block, 0, stream,
                       x, Wgc, bgc, Wpc, bpc, Wd1, bd1, Wd2, bd2,
                       (float*)d_out, B);
}